// Round 1
// baseline (147.269 us; speedup 1.0000x reference)
//
#include <hip/hip_runtime.h>

static constexpr int E = 256;
static constexpr int S = 4096;
static constexpr int BATCH = 4;

// Generic 64x64-tile fp32 GEMM: C[i,j] = scale * sum_k opA(i,k)*opB(k,j)
// TA=1: A stored [K][M] (opA(i,k)=A[k*E+i]); TA=0: A stored [M][K].
// TB=0: B stored [K][N]; TB=1: B stored [N][K].
// All leading dims are E=256 in this problem. blockIdx.z batches via strides.
template<int TA, int TB>
__global__ __launch_bounds__(256) void gemm64_kernel(
    const float* __restrict__ Ab, const float* __restrict__ Bb, float* __restrict__ Cb,
    int K, long sAz, long sBz, long sCz, float scale)
{
    const float* A  = Ab + (long)blockIdx.z * sAz;
    const float* Bm = Bb + (long)blockIdx.z * sBz;
    float*       C  = Cb + (long)blockIdx.z * sCz;
    const int i0 = blockIdx.y * 64;
    const int j0 = blockIdx.x * 64;
    __shared__ float As[64][68];  // [kk][ii], 68 keeps float4 alignment (272B rows)
    __shared__ float Bs[64][68];  // [kk][jj]
    const int tid = threadIdx.x;
    const int tx = tid & 15;
    const int ty = tid >> 4;
    float acc[4][4] = {{0.f}};
    for (int k0 = 0; k0 < K; k0 += 64) {
        if (TA) {
            #pragma unroll
            for (int r = 0; r < 4; ++r) {
                const int kk = (tid >> 4) + r * 16;
                const int ii = (tid & 15) * 4;
                const float4 v = *(const float4*)(A + (long)(k0 + kk) * E + i0 + ii);
                *(float4*)&As[kk][ii] = v;
            }
        } else {
            #pragma unroll
            for (int r = 0; r < 4; ++r) {
                const int ii = (tid >> 4) + r * 16;
                const int kk = (tid & 15) * 4;
                const float4 v = *(const float4*)(A + (long)(i0 + ii) * E + k0 + kk);
                As[kk+0][ii] = v.x; As[kk+1][ii] = v.y; As[kk+2][ii] = v.z; As[kk+3][ii] = v.w;
            }
        }
        if (!TB) {
            #pragma unroll
            for (int r = 0; r < 4; ++r) {
                const int kk = (tid >> 4) + r * 16;
                const int jj = (tid & 15) * 4;
                const float4 v = *(const float4*)(Bm + (long)(k0 + kk) * E + j0 + jj);
                *(float4*)&Bs[kk][jj] = v;
            }
        } else {
            #pragma unroll
            for (int r = 0; r < 4; ++r) {
                const int jj = (tid >> 4) + r * 16;
                const int kk = (tid & 15) * 4;
                const float4 v = *(const float4*)(Bm + (long)(j0 + jj) * E + k0 + kk);
                Bs[kk+0][jj] = v.x; Bs[kk+1][jj] = v.y; Bs[kk+2][jj] = v.z; Bs[kk+3][jj] = v.w;
            }
        }
        __syncthreads();
        #pragma unroll 8
        for (int kk = 0; kk < 64; ++kk) {
            const float4 av = *(const float4*)&As[kk][ty * 4];
            const float4 bv = *(const float4*)&Bs[kk][tx * 4];
            const float a_[4] = {av.x, av.y, av.z, av.w};
            const float b_[4] = {bv.x, bv.y, bv.z, bv.w};
            #pragma unroll
            for (int r = 0; r < 4; ++r)
                #pragma unroll
                for (int c = 0; c < 4; ++c)
                    acc[r][c] += a_[r] * b_[c];
        }
        __syncthreads();
    }
    #pragma unroll
    for (int r = 0; r < 4; ++r) {
        float4 v;
        v.x = acc[r][0] * scale; v.y = acc[r][1] * scale;
        v.z = acc[r][2] * scale; v.w = acc[r][3] * scale;
        *(float4*)(C + (long)(i0 + ty * 4 + r) * E + j0 + tx * 4) = v;
    }
}

// G[b] = sum over 4 K-chunk partials
__global__ __launch_bounds__(256) void reduce_g_kernel(
    const float* __restrict__ Gp, float* __restrict__ G)
{
    const long i = ((long)blockIdx.x * 256 + threadIdx.x) * 4;
    const long b = i >> 16;        // which batch's 65536-element block
    const long off = i & 65535;
    float4 s = make_float4(0.f, 0.f, 0.f, 0.f);
    #pragma unroll
    for (long c = 0; c < 4; ++c) {
        const float4 v = *(const float4*)(Gp + ((b * 4 + c) << 16) + off);
        s.x += v.x; s.y += v.y; s.z += v.z; s.w += v.w;
    }
    *(float4*)(G + i) = s;
}

// out_b[s,g] = sum_e x_b[s,e] * M_b[e,g]   (M already carries the 1e-11 scale)
// 64 rows x 256 cols per block; columns grouped tx*4 + g*64 to keep LDS reads 2-way.
__global__ __launch_bounds__(256) void final_kernel(
    const float* __restrict__ X, const float* __restrict__ Mb, float* __restrict__ Out)
{
    const int b = blockIdx.y;
    const float* A  = X  + (long)b * S * E;
    const float* Bm = Mb + (long)b * E * E;
    float*       C  = Out + (long)b * S * E;
    const int i0 = blockIdx.x * 64;
    __shared__ float As[32][68];    // [kk][ii]
    __shared__ float Bs[32][256];   // [kk][jj]
    const int tid = threadIdx.x;
    const int tx = tid & 15;
    const int ty = tid >> 4;
    float acc[4][16] = {{0.f}};
    for (int k0 = 0; k0 < E; k0 += 32) {
        #pragma unroll
        for (int r = 0; r < 2; ++r) {
            const int ii = (tid >> 3) + r * 32;
            const int kk = (tid & 7) * 4;
            const float4 v = *(const float4*)(A + (long)(i0 + ii) * E + k0 + kk);
            As[kk+0][ii] = v.x; As[kk+1][ii] = v.y; As[kk+2][ii] = v.z; As[kk+3][ii] = v.w;
        }
        #pragma unroll
        for (int r = 0; r < 8; ++r) {
            const int kk = (tid >> 6) + r * 4;
            const int jj = (tid & 63) * 4;
            const float4 v = *(const float4*)(Bm + (long)(k0 + kk) * E + jj);
            *(float4*)&Bs[kk][jj] = v;
        }
        __syncthreads();
        #pragma unroll 4
        for (int kk = 0; kk < 32; ++kk) {
            const float4 av = *(const float4*)&As[kk][ty * 4];
            const float a_[4] = {av.x, av.y, av.z, av.w};
            float b_[16];
            #pragma unroll
            for (int g = 0; g < 4; ++g) {
                const float4 bv = *(const float4*)&Bs[kk][tx * 4 + g * 64];
                b_[g*4+0] = bv.x; b_[g*4+1] = bv.y; b_[g*4+2] = bv.z; b_[g*4+3] = bv.w;
            }
            #pragma unroll
            for (int r = 0; r < 4; ++r)
                #pragma unroll
                for (int c = 0; c < 16; ++c)
                    acc[r][c] += a_[r] * b_[c];
        }
        __syncthreads();
    }
    #pragma unroll
    for (int r = 0; r < 4; ++r) {
        #pragma unroll
        for (int g = 0; g < 4; ++g) {
            float4 v;
            v.x = acc[r][g*4+0]; v.y = acc[r][g*4+1];
            v.z = acc[r][g*4+2]; v.w = acc[r][g*4+3];
            *(float4*)(C + (long)(i0 + ty * 4 + r) * E + tx * 4 + g * 64) = v;
        }
    }
}

extern "C" void kernel_launch(void* const* d_in, const int* in_sizes, int n_in,
                              void* d_out, int out_size, void* d_ws, size_t ws_size,
                              hipStream_t stream)
{
    const float* x  = (const float*)d_in[0];
    const float* Wq = (const float*)d_in[1];
    const float* Wk = (const float*)d_in[2];
    const float* Wv = (const float*)d_in[3];
    const float* Wo = (const float*)d_in[4];
    float* out = (float*)d_out;

    float* ws = (float*)d_ws;
    float* Gp = ws;                   // 16 * 65536   (4 batches x 4 K-chunks)
    float* G  = Gp + 16L * 65536;     // 4 * 65536
    float* P  = G  + 4L * 65536;      // 65536
    float* R  = P  + 65536;           // 65536
    float* T  = R  + 65536;           // 4 * 65536
    float* Mm = T  + 4L * 65536;      // 4 * 65536    total ~7.9 MB

    dim3 blk(256);

    // P = Wq^T Wk            P[e,f] = sum_g Wq[g,e] Wk[g,f]
    gemm64_kernel<1,0><<<dim3(4,4,1), blk, 0, stream>>>(Wq, Wk, P, 256, 0, 0, 0, 1.0f);
    // R = Wv^T Wo^T          R[e,g] = sum_f Wv[f,e] Wo[g,f]
    gemm64_kernel<1,1><<<dim3(4,4,1), blk, 0, stream>>>(Wv, Wo, R, 256, 0, 0, 0, 1.0f);
    // Gram partials: Gp[b*4+c] = x_b[chunk c]^T x_b[chunk c], K-chunk = 1024
    gemm64_kernel<1,0><<<dim3(4,4,16), blk, 0, stream>>>(x, x, Gp, 1024,
                                                         1024L * E, 1024L * E, 65536, 1.0f);
    // G_b = sum_c Gp[b*4+c]
    reduce_g_kernel<<<dim3(256), blk, 0, stream>>>(Gp, G);
    // T_b = P G_b
    gemm64_kernel<0,0><<<dim3(4,4,4), blk, 0, stream>>>(P, G, T, 256, 0, 65536, 65536, 1.0f);
    // M_b = 1e-11 * T_b R
    gemm64_kernel<0,0><<<dim3(4,4,4), blk, 0, stream>>>(T, R, Mm, 256, 65536, 0, 65536, 1e-11f);
    // out_b = x_b M_b
    final_kernel<<<dim3(S / 64, BATCH), blk, 0, stream>>>(x, Mm, out);
}

// Round 2
// 90.155 us; speedup vs baseline: 1.6335x; 1.6335x over previous
//
#include <hip/hip_runtime.h>

static constexpr int E = 256;
static constexpr int S = 4096;

typedef __attribute__((ext_vector_type(8))) short short8v;   // 8 bf16 (4 VGPRs)
typedef __attribute__((ext_vector_type(4))) float f32x4;     // 4 fp32 acc

static __device__ __forceinline__ unsigned short f2bf(float f) {
    union { float f; unsigned u; } v; v.f = f;
    unsigned r = v.u + 0x7fffu + ((v.u >> 16) & 1u);   // RNE
    return (unsigned short)(r >> 16);
}

static __device__ __forceinline__ f32x4 mfma16(short8v a, short8v b, f32x4 c) {
    return __builtin_amdgcn_mfma_f32_16x16x32_bf16(a, b, c, 0, 0, 0);
}

// ---------------------------------------------------------------------------
// x fp32 [16384][256]  ->  Xb bf16 [16384][256]  and  XT bf16 [b][256][4096]
// 64x64 tiles, LDS transpose.
__global__ __launch_bounds__(256) void convert_kernel(
    const float* __restrict__ X, unsigned short* __restrict__ Xb,
    unsigned short* __restrict__ XT)
{
    __shared__ unsigned short Ls[64][66];
    const int t  = threadIdx.x;
    const int e0 = blockIdx.x * 64;
    const int s0 = blockIdx.y * 64;
    const int lr = t >> 2;          // local row (s)
    const int lc = (t & 3) * 16;    // local col segment (e)
    const float* src = X + (long)(s0 + lr) * E + e0 + lc;
    short8v v0, v1;
    #pragma unroll
    for (int q = 0; q < 4; ++q) {
        const float4 v = *(const float4*)(src + q * 4);
        const unsigned short b0 = f2bf(v.x), b1 = f2bf(v.y), b2 = f2bf(v.z), b3 = f2bf(v.w);
        Ls[lc + q*4 + 0][lr] = b0; Ls[lc + q*4 + 1][lr] = b1;
        Ls[lc + q*4 + 2][lr] = b2; Ls[lc + q*4 + 3][lr] = b3;
        if (q < 2) { v0[q*4+0]=(short)b0; v0[q*4+1]=(short)b1; v0[q*4+2]=(short)b2; v0[q*4+3]=(short)b3; }
        else { v1[(q-2)*4+0]=(short)b0; v1[(q-2)*4+1]=(short)b1; v1[(q-2)*4+2]=(short)b2; v1[(q-2)*4+3]=(short)b3; }
    }
    unsigned short* dstb = Xb + (long)(s0 + lr) * E + e0 + lc;
    *(short8v*)(dstb)     = v0;
    *(short8v*)(dstb + 8) = v1;
    __syncthreads();
    const int b  = s0 >> 12;
    const int sl = s0 & 4095;
    short8v w0, w1;
    #pragma unroll
    for (int j = 0; j < 8; ++j) { w0[j] = (short)Ls[lr][lc + j]; w1[j] = (short)Ls[lr][lc + 8 + j]; }
    unsigned short* dstt = XT + ((long)(b * E + e0 + lr)) * S + sl + lc;
    *(short8v*)(dstt)     = w0;
    *(short8v*)(dstt + 8) = w1;
}

// ---------------------------------------------------------------------------
// Gram partials via MFMA: Gp[b][c][e][f] = sum_{s in chunk c} x[s,e] x[s,f]
// 1 wave = 32x32 output tile over K-chunk 1024. grid (16, batch=4, chunk=4), 256 thr.
__global__ __launch_bounds__(256) void gram_kernel(
    const unsigned short* __restrict__ XT, float* __restrict__ Gp)
{
    const int b = blockIdx.y, c = blockIdx.z;
    const int w = blockIdx.x * 4 + (threadIdx.x >> 6);   // 0..63
    const int ti = w >> 3, tj = w & 7;
    const int lane = threadIdx.x & 63;
    const int lr = lane & 15, lg = lane >> 4;
    const unsigned short* base = XT + (long)b * E * S + c * 1024 + lg * 8;
    const unsigned short* pa0 = base + (long)(ti * 32 + lr) * S;
    const unsigned short* pa1 = pa0 + 16 * S;
    const unsigned short* pb0 = base + (long)(tj * 32 + lr) * S;
    const unsigned short* pb1 = pb0 + 16 * S;
    f32x4 acc00 = {0,0,0,0}, acc01 = {0,0,0,0}, acc10 = {0,0,0,0}, acc11 = {0,0,0,0};
    #pragma unroll 4
    for (int k = 0; k < 1024; k += 32) {
        const short8v a0 = *(const short8v*)(pa0 + k);
        const short8v a1 = *(const short8v*)(pa1 + k);
        const short8v b0 = *(const short8v*)(pb0 + k);
        const short8v b1 = *(const short8v*)(pb1 + k);
        acc00 = mfma16(a0, b0, acc00);
        acc01 = mfma16(a0, b1, acc01);
        acc10 = mfma16(a1, b0, acc10);
        acc11 = mfma16(a1, b1, acc11);
    }
    float* out = Gp + (((long)b * 4 + c) << 16);
    #pragma unroll
    for (int r = 0; r < 4; ++r) {
        const int e0 = ti * 32 + lg * 4 + r;
        const int f0 = tj * 32 + lr;
        out[(e0     ) * E + f0     ] = acc00[r];
        out[(e0     ) * E + f0 + 16] = acc01[r];
        out[(e0 + 16) * E + f0     ] = acc10[r];
        out[(e0 + 16) * E + f0 + 16] = acc11[r];
    }
}

// ---------------------------------------------------------------------------
// P = Wq^T Wk (z=0), R = Wv^T Wo^T (z=1). fp32 64x64 tile, K=256.
__global__ __launch_bounds__(256) void pr_kernel(
    const float* __restrict__ Wq, const float* __restrict__ Wk,
    const float* __restrict__ Wv, const float* __restrict__ Wo,
    float* __restrict__ P, float* __restrict__ R)
{
    const int mode = blockIdx.z;
    const float* A  = mode ? Wv : Wq;
    const float* Bm = mode ? Wo : Wk;
    float*       C  = mode ? R  : P;
    const int i0 = blockIdx.y * 64, j0 = blockIdx.x * 64;
    __shared__ float As[64][68];
    __shared__ float Bs[64][68];
    const int tid = threadIdx.x, tx = tid & 15, ty = tid >> 4;
    float acc[4][4] = {{0.f}};
    for (int k0 = 0; k0 < E; k0 += 64) {
        #pragma unroll
        for (int r = 0; r < 4; ++r) {        // A^T: A[k][i]
            const int kk = (tid >> 4) + r * 16;
            const int ii = (tid & 15) * 4;
            *(float4*)&As[kk][ii] = *(const float4*)(A + (long)(k0 + kk) * E + i0 + ii);
        }
        if (mode == 0) {
            #pragma unroll
            for (int r = 0; r < 4; ++r) {    // B[k][j]
                const int kk = (tid >> 4) + r * 16;
                const int jj = (tid & 15) * 4;
                *(float4*)&Bs[kk][jj] = *(const float4*)(Bm + (long)(k0 + kk) * E + j0 + jj);
            }
        } else {
            #pragma unroll
            for (int r = 0; r < 4; ++r) {    // B^T: B[j][k]
                const int jj = (tid >> 4) + r * 16;
                const int kk = (tid & 15) * 4;
                const float4 v = *(const float4*)(Bm + (long)(j0 + jj) * E + k0 + kk);
                Bs[kk+0][jj] = v.x; Bs[kk+1][jj] = v.y; Bs[kk+2][jj] = v.z; Bs[kk+3][jj] = v.w;
            }
        }
        __syncthreads();
        #pragma unroll 8
        for (int kk = 0; kk < 64; ++kk) {
            const float4 av = *(const float4*)&As[kk][ty * 4];
            const float4 bv = *(const float4*)&Bs[kk][tx * 4];
            const float a_[4] = {av.x, av.y, av.z, av.w};
            const float b_[4] = {bv.x, bv.y, bv.z, bv.w};
            #pragma unroll
            for (int r = 0; r < 4; ++r)
                #pragma unroll
                for (int c = 0; c < 4; ++c) acc[r][c] += a_[r] * b_[c];
        }
        __syncthreads();
    }
    #pragma unroll
    for (int r = 0; r < 4; ++r) {
        float4 v; v.x = acc[r][0]; v.y = acc[r][1]; v.z = acc[r][2]; v.w = acc[r][3];
        *(float4*)(C + (long)(i0 + ty * 4 + r) * E + j0 + tx * 4) = v;
    }
}

// ---------------------------------------------------------------------------
// T_b = P @ (sum_c Gp[b][c]).  fp32 64x64, grid (4,4,batch).
__global__ __launch_bounds__(256) void t_kernel(
    const float* __restrict__ P, const float* __restrict__ Gp, float* __restrict__ T)
{
    const int b = blockIdx.z;
    const float* Gb = Gp + ((long)b * 4 << 16);
    float* C = T + ((long)b << 16);
    const int i0 = blockIdx.y * 64, j0 = blockIdx.x * 64;
    __shared__ float As[64][68];
    __shared__ float Bs[64][68];
    const int tid = threadIdx.x, tx = tid & 15, ty = tid >> 4;
    float acc[4][4] = {{0.f}};
    for (int k0 = 0; k0 < E; k0 += 64) {
        #pragma unroll
        for (int r = 0; r < 4; ++r) {        // A[i][k] = P
            const int ii = (tid >> 4) + r * 16;
            const int kk = (tid & 15) * 4;
            const float4 v = *(const float4*)(P + (long)(i0 + ii) * E + k0 + kk);
            As[kk+0][ii] = v.x; As[kk+1][ii] = v.y; As[kk+2][ii] = v.z; As[kk+3][ii] = v.w;
        }
        #pragma unroll
        for (int r = 0; r < 4; ++r) {        // B[k][j] = sum_c Gp
            const int kk = (tid >> 4) + r * 16;
            const int jj = (tid & 15) * 4;
            float4 s = make_float4(0.f, 0.f, 0.f, 0.f);
            #pragma unroll
            for (int c = 0; c < 4; ++c) {
                const float4 v = *(const float4*)(Gb + ((long)c << 16) + (long)(k0 + kk) * E + j0 + jj);
                s.x += v.x; s.y += v.y; s.z += v.z; s.w += v.w;
            }
            *(float4*)&Bs[kk][jj] = s;
        }
        __syncthreads();
        #pragma unroll 8
        for (int kk = 0; kk < 64; ++kk) {
            const float4 av = *(const float4*)&As[kk][ty * 4];
            const float4 bv = *(const float4*)&Bs[kk][tx * 4];
            const float a_[4] = {av.x, av.y, av.z, av.w};
            const float b_[4] = {bv.x, bv.y, bv.z, bv.w};
            #pragma unroll
            for (int r = 0; r < 4; ++r)
                #pragma unroll
                for (int c = 0; c < 4; ++c) acc[r][c] += a_[r] * b_[c];
        }
        __syncthreads();
    }
    #pragma unroll
    for (int r = 0; r < 4; ++r) {
        float4 v; v.x = acc[r][0]; v.y = acc[r][1]; v.z = acc[r][2]; v.w = acc[r][3];
        *(float4*)(C + (long)(i0 + ty * 4 + r) * E + j0 + tx * 4) = v;
    }
}

// ---------------------------------------------------------------------------
// MT[b][g][e] = bf16( 1e-11 * (T_b @ R)[e][g] ).  fp32 64x64, bf16-transposed epilogue.
__global__ __launch_bounds__(256) void m_kernel(
    const float* __restrict__ T, const float* __restrict__ R, unsigned short* __restrict__ MT)
{
    const int b = blockIdx.z;
    const float* A = T + ((long)b << 16);
    unsigned short* C = MT + ((long)b << 16);
    const int i0 = blockIdx.y * 64, j0 = blockIdx.x * 64;
    __shared__ float As[64][68];
    __shared__ float Bs[64][68];
    const int tid = threadIdx.x, tx = tid & 15, ty = tid >> 4;
    float acc[4][4] = {{0.f}};
    for (int k0 = 0; k0 < E; k0 += 64) {
        #pragma unroll
        for (int r = 0; r < 4; ++r) {        // A[i][k] = T_b
            const int ii = (tid >> 4) + r * 16;
            const int kk = (tid & 15) * 4;
            const float4 v = *(const float4*)(A + (long)(i0 + ii) * E + k0 + kk);
            As[kk+0][ii] = v.x; As[kk+1][ii] = v.y; As[kk+2][ii] = v.z; As[kk+3][ii] = v.w;
        }
        #pragma unroll
        for (int r = 0; r < 4; ++r) {        // B[k][j] = R
            const int kk = (tid >> 4) + r * 16;
            const int jj = (tid & 15) * 4;
            *(float4*)&Bs[kk][jj] = *(const float4*)(R + (long)(k0 + kk) * E + j0 + jj);
        }
        __syncthreads();
        #pragma unroll 8
        for (int kk = 0; kk < 64; ++kk) {
            const float4 av = *(const float4*)&As[kk][ty * 4];
            const float4 bv = *(const float4*)&Bs[kk][tx * 4];
            const float a_[4] = {av.x, av.y, av.z, av.w};
            const float b_[4] = {bv.x, bv.y, bv.z, bv.w};
            #pragma unroll
            for (int r = 0; r < 4; ++r)
                #pragma unroll
                for (int c = 0; c < 4; ++c) acc[r][c] += a_[r] * b_[c];
        }
        __syncthreads();
    }
    #pragma unroll
    for (int r = 0; r < 4; ++r)
        #pragma unroll
        for (int c = 0; c < 4; ++c)
            C[(long)(j0 + tx * 4 + c) * E + (i0 + ty * 4 + r)] = f2bf(acc[r][c] * 1e-11f);
}

// ---------------------------------------------------------------------------
// out = Xb @ M_b via MFMA. 1 wave = 32 rows x 64 cols; block = 4 waves = 128 rows.
// grid (4 col-tiles, 128 row-blocks).
__global__ __launch_bounds__(256) void final_kernel(
    const unsigned short* __restrict__ Xb, const unsigned short* __restrict__ MT,
    float* __restrict__ Out)
{
    const int s0 = blockIdx.y * 128 + (threadIdx.x >> 6) * 32;
    const int g0 = blockIdx.x * 64;
    const int b  = s0 >> 12;
    const int lane = threadIdx.x & 63;
    const int lr = lane & 15, lg = lane >> 4;
    const unsigned short* pa0 = Xb + (long)(s0 + lr) * E + lg * 8;
    const unsigned short* pa1 = pa0 + 16 * E;
    const unsigned short* pb  = MT + ((long)b * E + g0 + lr) * E + lg * 8;
    f32x4 acc[2][4] = {};
    #pragma unroll
    for (int k = 0; k < E; k += 32) {
        const short8v a0 = *(const short8v*)(pa0 + k);
        const short8v a1 = *(const short8v*)(pa1 + k);
        #pragma unroll
        for (int ni = 0; ni < 4; ++ni) {
            const short8v bf = *(const short8v*)(pb + (long)ni * 16 * E + k);
            acc[0][ni] = mfma16(a0, bf, acc[0][ni]);
            acc[1][ni] = mfma16(a1, bf, acc[1][ni]);
        }
    }
    #pragma unroll
    for (int mi = 0; mi < 2; ++mi)
        #pragma unroll
        for (int r = 0; r < 4; ++r) {
            float* row = Out + (long)(s0 + mi * 16 + lg * 4 + r) * E + g0 + lr;
            #pragma unroll
            for (int ni = 0; ni < 4; ++ni) row[ni * 16] = acc[mi][ni][r];
        }
}

// ---------------------------------------------------------------------------
extern "C" void kernel_launch(void* const* d_in, const int* in_sizes, int n_in,
                              void* d_out, int out_size, void* d_ws, size_t ws_size,
                              hipStream_t stream)
{
    const float* x  = (const float*)d_in[0];
    const float* Wq = (const float*)d_in[1];
    const float* Wk = (const float*)d_in[2];
    const float* Wv = (const float*)d_in[3];
    const float* Wo = (const float*)d_in[4];
    float* out = (float*)d_out;

    char* ws = (char*)d_ws;
    unsigned short* Xb = (unsigned short*)(ws);                    //  8.39 MB
    unsigned short* XT = (unsigned short*)(ws + 8388608);          //  8.39 MB
    float*          Gp = (float*)(ws + 16777216);                  //  4.19 MB
    float*          P  = (float*)(ws + 20971520);                  //  0.26 MB
    float*          R  = (float*)(ws + 21233664);                  //  0.26 MB
    float*          T  = (float*)(ws + 21495808);                  //  1.05 MB
    unsigned short* MT = (unsigned short*)(ws + 22544384);         //  0.52 MB (ends ~23 MB)

    dim3 blk(256);
    convert_kernel<<<dim3(4, 256),   blk, 0, stream>>>(x, Xb, XT);
    pr_kernel     <<<dim3(4, 4, 2),  blk, 0, stream>>>(Wq, Wk, Wv, Wo, P, R);
    gram_kernel   <<<dim3(16, 4, 4), blk, 0, stream>>>(XT, Gp);
    t_kernel      <<<dim3(4, 4, 4),  blk, 0, stream>>>(P, Gp, T);
    m_kernel      <<<dim3(4, 4, 4),  blk, 0, stream>>>(T, R, MT);
    final_kernel  <<<dim3(4, 128),   blk, 0, stream>>>(Xb, MT, out);
}